// Round 2
// baseline (1530.950 us; speedup 1.0000x reference)
//
#include <hip/hip_runtime.h>

#define B_TOTAL 8192
#define T_FULL  100
#define XD      256
#define T0      30
#define TW      70      // time window length (30:100)
#define KS      50      // conv kernel size
#define NT      21      // TW - KS + 1 output positions
#define YOUT    300     // Y_DIM * 50
#define NB      8       // batches per block (fc_w L2-traffic amortization)

__global__ __launch_bounds__(256, 3)
void tiancnn_fused(const float* __restrict__ seq,
                   const float* __restrict__ conv_w,
                   const float* __restrict__ fc_w,
                   float* __restrict__ out) {
    __shared__ float feat[NB][XD];

    const int f  = threadIdx.x;          // feature index 0..255
    const int b0 = blockIdx.x * NB;

    // Per-feature depthwise conv weights -> registers (L2-resident after 1st block)
    float w[KS];
#pragma unroll
    for (int k = 0; k < KS; ++k) w[k] = conv_w[f * KS + k];

    // ---- Conv + ReLU + time-max, streaming-accumulator form ----
#pragma unroll 1
    for (int nb = 0; nb < NB; ++nb) {
        const float* xp = seq + ((size_t)(b0 + nb) * T_FULL + T0) * XD + f;

        float acc[NT];
#pragma unroll
        for (int t = 0; t < NT; ++t) acc[t] = 0.f;

        // For each incoming sample x_j, update every window it participates in.
        // Both loops fully unrolled: guard + weight index fold to compile-time
        // constants -> 1050 static-index FMAs, no xv[] array, ~80 live VGPRs.
#pragma unroll
        for (int j = 0; j < TW; ++j) {
            const float x = xp[(size_t)j * XD];   // 64 lanes -> 256B contiguous
#pragma unroll
            for (int t = 0; t < NT; ++t) {
                if (j - t >= 0 && j - t < KS) {
                    acc[t] = fmaf(x, w[j - t], acc[t]);
                }
            }
        }

        // max(relu(y)) == max(0, max_t y[t]) — pairwise tree
        float m = 0.f;
#pragma unroll
        for (int t = 0; t < NT; ++t) m = fmaxf(m, acc[t]);
        feat[nb][f] = m;
    }
    __syncthreads();

    // ---- FC: out[b0+nb][o] = dot(feat[nb], fc_w[o]) ----
    for (int idx = threadIdx.x; idx < NB * YOUT; idx += 256) {
        const int nb = idx / YOUT;
        const int o  = idx - nb * YOUT;
        const float4* wrow = reinterpret_cast<const float4*>(fc_w + (size_t)o * XD);
        const float*  fv   = feat[nb];
        float acc = 0.f;
#pragma unroll
        for (int q = 0; q < XD / 4; ++q) {
            const float4 wv = wrow[q];
            acc = fmaf(wv.x, fv[4 * q + 0], acc);
            acc = fmaf(wv.y, fv[4 * q + 1], acc);
            acc = fmaf(wv.z, fv[4 * q + 2], acc);
            acc = fmaf(wv.w, fv[4 * q + 3], acc);
        }
        out[(size_t)(b0 + nb) * YOUT + o] = acc;
    }
}

extern "C" void kernel_launch(void* const* d_in, const int* in_sizes, int n_in,
                              void* d_out, int out_size, void* d_ws, size_t ws_size,
                              hipStream_t stream) {
    const float* seq    = (const float*)d_in[0];
    const float* conv_w = (const float*)d_in[1];
    const float* fc_w   = (const float*)d_in[2];
    float*       out    = (float*)d_out;

    tiancnn_fused<<<dim3(B_TOTAL / NB), dim3(256), 0, stream>>>(seq, conv_w, fc_w, out);
}

// Round 3
// 1169.894 us; speedup vs baseline: 1.3086x; 1.3086x over previous
//
#include <hip/hip_runtime.h>

#define B_TOTAL 8192
#define T_FULL  100
#define XD      256
#define T0      30
#define TW      70      // time window length (30:100)
#define KS      50      // conv kernel size
#define KH      25      // half-kernel (k-phase split)
#define NT      21      // TW - KS + 1 output positions
#define YOUT    300     // Y_DIM * 50
#define NB      4       // batches per block

__global__ __launch_bounds__(256, 4)
void tiancnn_fused(const float* __restrict__ seq,
                   const float* __restrict__ conv_w,
                   const float* __restrict__ fc_w,
                   float* __restrict__ out) {
    __shared__ float feat[NB][XD];

    const int f  = threadIdx.x;          // feature index 0..255
    const int b0 = blockIdx.x * NB;

#pragma unroll 1
    for (int nb = 0; nb < NB; ++nb) {
        const float* xp = seq + ((size_t)(b0 + nb) * T_FULL + T0) * XD + f;

        float acc[NT];
#pragma unroll
        for (int t = 0; t < NT; ++t) acc[t] = 0.f;

        // ---- Phase 0: taps k = 0..24, needs x[0..45] (46 values) ----
        {
            float w0[KH];
#pragma unroll
            for (int k = 0; k < KH; ++k) w0[k] = conv_w[f * KS + k];

            float xv[NT + KH];              // 46
#pragma unroll
            for (int j = 0; j < NT + KH; ++j) xv[j] = xp[(size_t)j * XD];

#pragma unroll
            for (int t = 0; t < NT; ++t)
#pragma unroll
                for (int k = 0; k < KH; ++k)
                    acc[t] = fmaf(xv[t + k], w0[k], acc[t]);
        }

        // ---- Phase 1: taps k = 25..49, needs x[25..69] (45 values) ----
        {
            float w1[KH];
#pragma unroll
            for (int k = 0; k < KH; ++k) w1[k] = conv_w[f * KS + KH + k];

            float xv[NT + KH - 1];          // 45
#pragma unroll
            for (int j = 0; j < NT + KH - 1; ++j) xv[j] = xp[(size_t)(KH + j) * XD];

#pragma unroll
            for (int t = 0; t < NT; ++t)
#pragma unroll
                for (int k = 0; k < KH; ++k)
                    acc[t] = fmaf(xv[t + k], w1[k], acc[t]);
        }

        // max(relu(y)) == max(0, max_t y[t])
        float m = 0.f;
#pragma unroll
        for (int t = 0; t < NT; ++t) m = fmaxf(m, acc[t]);
        feat[nb][f] = m;
    }
    __syncthreads();

    // ---- FC: out[b0+nb][o] = dot(feat[nb], fc_w[o]) ----
    for (int idx = threadIdx.x; idx < NB * YOUT; idx += 256) {
        const int nb = idx / YOUT;
        const int o  = idx - nb * YOUT;
        const float4* wrow = reinterpret_cast<const float4*>(fc_w + (size_t)o * XD);
        const float*  fv   = feat[nb];
        float acc = 0.f;
#pragma unroll
        for (int q = 0; q < XD / 4; ++q) {
            const float4 wv = wrow[q];
            acc = fmaf(wv.x, fv[4 * q + 0], acc);
            acc = fmaf(wv.y, fv[4 * q + 1], acc);
            acc = fmaf(wv.z, fv[4 * q + 2], acc);
            acc = fmaf(wv.w, fv[4 * q + 3], acc);
        }
        out[(size_t)(b0 + nb) * YOUT + o] = acc;
    }
}

extern "C" void kernel_launch(void* const* d_in, const int* in_sizes, int n_in,
                              void* d_out, int out_size, void* d_ws, size_t ws_size,
                              hipStream_t stream) {
    const float* seq    = (const float*)d_in[0];
    const float* conv_w = (const float*)d_in[1];
    const float* fc_w   = (const float*)d_in[2];
    float*       out    = (float*)d_out;

    tiancnn_fused<<<dim3(B_TOTAL / NB), dim3(256), 0, stream>>>(seq, conv_w, fc_w, out);
}

// Round 4
// 1157.077 us; speedup vs baseline: 1.3231x; 1.0111x over previous
//
#include <hip/hip_runtime.h>

#define B_TOTAL 8192
#define T_FULL  100
#define XD      256
#define T0      30
#define TW      70      // time window length (30:100)
#define KS      50      // conv kernel size
#define KH      25      // half-kernel (k-phase split)
#define NT      21      // TW - KS + 1 output positions
#define YOUT    300     // Y_DIM * 50
#define NB      4       // batches per block

// Pin waves/EU to exactly 4: scheduler occupancy target == allocator budget
// (128 VGPR). launch_bounds alone only sets the MIN; the backend was targeting
// 8 waves/EU (64 VGPR) and spilling ~1.9 GB to scratch (rounds 2-3).
__global__ __attribute__((amdgpu_flat_work_group_size(256, 256),
                          amdgpu_waves_per_eu(4, 4)))
void tiancnn_fused(const float* __restrict__ seq,
                   const float* __restrict__ conv_w,
                   const float* __restrict__ fc_w,
                   float* __restrict__ out) {
    __shared__ float feat[NB][XD];

    const int f  = threadIdx.x;          // feature index 0..255
    const int b0 = blockIdx.x * NB;

#pragma unroll 1
    for (int nb = 0; nb < NB; ++nb) {
        const float* xp = seq + ((size_t)(b0 + nb) * T_FULL + T0) * XD + f;

        float acc[NT];
#pragma unroll
        for (int t = 0; t < NT; ++t) acc[t] = 0.f;

        // ---- Phase 0: taps k = 0..24, needs x[0..45] (46 values) ----
        {
            float w0[KH];
#pragma unroll
            for (int k = 0; k < KH; ++k) w0[k] = conv_w[f * KS + k];

            float xv[NT + KH];              // 46
#pragma unroll
            for (int j = 0; j < NT + KH; ++j) xv[j] = xp[(size_t)j * XD];

#pragma unroll
            for (int t = 0; t < NT; ++t)
#pragma unroll
                for (int k = 0; k < KH; ++k)
                    acc[t] = fmaf(xv[t + k], w0[k], acc[t]);
        }

        // ---- Phase 1: taps k = 25..49, needs x[25..69] (45 values) ----
        {
            float w1[KH];
#pragma unroll
            for (int k = 0; k < KH; ++k) w1[k] = conv_w[f * KS + KH + k];

            float xv[NT + KH - 1];          // 45
#pragma unroll
            for (int j = 0; j < NT + KH - 1; ++j) xv[j] = xp[(size_t)(KH + j) * XD];

#pragma unroll
            for (int t = 0; t < NT; ++t)
#pragma unroll
                for (int k = 0; k < KH; ++k)
                    acc[t] = fmaf(xv[t + k], w1[k], acc[t]);
        }

        // max(relu(y)) == max(0, max_t y[t])
        float m = 0.f;
#pragma unroll
        for (int t = 0; t < NT; ++t) m = fmaxf(m, acc[t]);
        feat[nb][f] = m;
    }
    __syncthreads();

    // ---- FC: out[b0+nb][o] = dot(feat[nb], fc_w[o]) ----
    for (int idx = threadIdx.x; idx < NB * YOUT; idx += 256) {
        const int nb = idx / YOUT;
        const int o  = idx - nb * YOUT;
        const float4* wrow = reinterpret_cast<const float4*>(fc_w + (size_t)o * XD);
        const float*  fv   = feat[nb];
        float acc = 0.f;
#pragma unroll
        for (int q = 0; q < XD / 4; ++q) {
            const float4 wv = wrow[q];
            acc = fmaf(wv.x, fv[4 * q + 0], acc);
            acc = fmaf(wv.y, fv[4 * q + 1], acc);
            acc = fmaf(wv.z, fv[4 * q + 2], acc);
            acc = fmaf(wv.w, fv[4 * q + 3], acc);
        }
        out[(size_t)(b0 + nb) * YOUT + o] = acc;
    }
}

extern "C" void kernel_launch(void* const* d_in, const int* in_sizes, int n_in,
                              void* d_out, int out_size, void* d_ws, size_t ws_size,
                              hipStream_t stream) {
    const float* seq    = (const float*)d_in[0];
    const float* conv_w = (const float*)d_in[1];
    const float* fc_w   = (const float*)d_in[2];
    float*       out    = (float*)d_out;

    tiancnn_fused<<<dim3(B_TOTAL / NB), dim3(256), 0, stream>>>(seq, conv_w, fc_w, out);
}